// Round 8
// baseline (940.017 us; speedup 1.0000x reference)
//
#include <hip/hip_runtime.h>
#include <cstdint>
#include <math.h>

#define B_  64
#define L_  256
#define V_  256
#define E_  256
#define H_  1024
#define H3  3072

typedef __bf16 bf16x8 __attribute__((ext_vector_type(8)));
typedef float  f32x4  __attribute__((ext_vector_type(4)));

__device__ __forceinline__ unsigned short f2bf(float f) {
    union { float f; unsigned u; } v; v.f = f;
    unsigned r = v.u + 0x7fffu + ((v.u >> 16) & 1u);   // round-to-nearest-even
    return (unsigned short)(r >> 16);
}

// ok iff NO 16-bit half of any dword equals the 0xAAAA poison sentinel
__device__ __forceinline__ int chunk_ok(bf16x8 v) {
    union { bf16x8 b; unsigned u[4]; } cv; cv.b = v;
    int ok = 1;
#pragma unroll
    for (int i = 0; i < 4; i++) {
        unsigned x = cv.u[i] ^ 0xAAAAAAAAu;
        ok &= (int)((x & 0xFFFFu) != 0u) & (int)((x >> 16) != 0u);
    }
    return ok;
}

__device__ __forceinline__ float sigmoid_f(float x) {
    return __builtin_amdgcn_rcpf(1.0f + __expf(-x));
}
__device__ __forceinline__ float tanh_f(float x) {
    // tanh(x) = 1 - 2/(e^{2x}+1); saturates correctly at +-inf
    return 1.0f - 2.0f * __builtin_amdgcn_rcpf(1.0f + __expf(2.0f * x));
}

// ---- single prep kernel: 3 transposes + emb convert + h0 zero + hist poison ----
// grid regions: [0,3072) WhT tiles; [3072,3840) WiT; [3840,4096) WoutT;
// [4096,4352) embB+h0; [4352,12544) poison slots 1..256.
__global__ __launch_bounds__(256) void prep_all(
        const float* __restrict__ Wh, const float* __restrict__ Wi,
        const float* __restrict__ Wout, const float* __restrict__ emb,
        unsigned short* __restrict__ WhT, unsigned short* __restrict__ WiT,
        unsigned short* __restrict__ WoutT, unsigned short* __restrict__ embB,
        unsigned short* __restrict__ h0b, uint4* __restrict__ poison) {
    __shared__ unsigned short tile[32][34];
    int bid = blockIdx.x;
    const float* src; unsigned short* dst; int rows, cols, nt, kt;
    if (bid < 3072)      { src = Wh;   dst = WhT;   rows = H_; cols = H3; nt = bid % 96; kt = bid / 96; }
    else if (bid < 3840) { int b = bid - 3072; src = Wi;   dst = WiT;   rows = E_; cols = H3; nt = b % 96; kt = b / 96; }
    else if (bid < 4096) { int b = bid - 3840; src = Wout; dst = WoutT; rows = H_; cols = V_; nt = b % 8;  kt = b / 8; }
    else if (bid < 4352) {
        int idx = (bid - 4096) * 256 + threadIdx.x;   // 65536 = V*E = B*H
        embB[idx] = f2bf(emb[idx]);
        h0b[idx]  = 0;
        return;
    } else {
        size_t T = (size_t)(bid - 4352) * 256 + threadIdx.x;   // 2M uint4 = 33.55 MB
        uint4 v; v.x = v.y = v.z = v.w = 0xAAAAAAAAu;
        poison[T] = v;
        return;
    }
    int n0 = nt * 32, k0 = kt * 32;
    int tx = threadIdx.x & 31, ty = threadIdx.x >> 5;
#pragma unroll
    for (int j = 0; j < 32; j += 8)
        tile[tx][ty + j] = f2bf(src[(size_t)(k0 + ty + j) * cols + (n0 + tx)]);
    __syncthreads();
#pragma unroll
    for (int j = 0; j < 32; j += 8)
        dst[(size_t)(n0 + ty + j) * rows + (k0 + tx)] = tile[ty + j][tx];
}

// ---- phase 2: persistent GRU; round-7 structure exactly, with ONE delta:
//      group-B loads are issued in the SAME poll iteration as group A
//      (same program point, phase preserved; A-gated break; sleep per miss)
//      so B's RTT completes alongside A's and the later B-wait is free. ----
__global__ __launch_bounds__(256, 1) void gru_persistent(
        unsigned short* __restrict__ hist,        // [257][B][H], slot0=0, rest poisoned
        const unsigned short* __restrict__ WhT,   // [3H][H]
        const unsigned short* __restrict__ WiT,   // [3H][E]
        const unsigned short* __restrict__ embB,  // [V][E]
        const int* __restrict__ tokens,           // [B][L]
        const float* __restrict__ bh,
        unsigned short* __restrict__ yB) {        // [B][L][H]
    __shared__ f32x4 red[2][4][6][64];            // [parity][wave][slot][lane]

    int bid = blockIdx.x;
    int btile = bid & 3;
    int jtile = bid >> 2;
    int wave = threadIdx.x >> 6, lane = threadIdx.x & 63;
    int l16 = lane & 15, q = lane >> 4;
    int b0 = btile * 16, j0 = jtile * 16;
    int kbase = wave * 256;

    // ---- pin Wh fragments (96 VGPR/lane) ----
    bf16x8 Wreg[3][8];
#pragma unroll
    for (int g = 0; g < 3; g++) {
        const bf16x8* Brow = (const bf16x8*)(WhT + (size_t)(g * H_ + j0 + l16) * H_);
#pragma unroll
        for (int kk = 0; kk < 8; kk++) {
            Wreg[g][kk] = Brow[(kbase >> 3) + kk * 4 + q];
            asm volatile("" : "+v"(Wreg[g][kk]));
        }
    }
    // ---- pin Wi fragments (24 VGPR/lane) ----
    bf16x8 Wxreg[3][2];
#pragma unroll
    for (int g = 0; g < 3; g++) {
        const bf16x8* Bx = (const bf16x8*)(WiT + (size_t)(g * H_ + j0 + l16) * E_);
#pragma unroll
        for (int c = 0; c < 2; c++) {
            Wxreg[g][c] = Bx[wave * 8 + c * 4 + q];
            asm volatile("" : "+v"(Wxreg[g][c]));
        }
    }

    // ---- per-thread gate mapping / biases / fp32 state ----
    int Lp  = threadIdx.x & 63;
    int reg = threadIdx.x >> 6;
    int b_local = (Lp >> 4) * 4 + reg;
    int j_local = Lp & 15;
    int b = b0 + b_local, jg = j0 + j_local;
    float bhr = bh[jg];
    float bhz = bh[H_ + jg];
    float bhn = bh[2 * H_ + jg];
    asm volatile("" : "+v"(bhr), "+v"(bhz), "+v"(bhn));
    float hreg = 0.0f;

    const int tokrow = (b0 + l16) * L_;

    for (int t = 0; t < L_; t++) {
        const unsigned short* hist_t  = hist + (size_t)t * (B_ * H_);
        unsigned short*       hist_t1 = hist + (size_t)(t + 1) * (B_ * H_);

        // ---- xw partials (h-independent; before the poll) ----
        int tok = tokens[tokrow + t];
        const bf16x8* Ax = (const bf16x8*)(embB + (size_t)tok * E_);
        bf16x8 ax0 = Ax[wave * 8 + q];
        bf16x8 ax1 = Ax[wave * 8 + 4 + q];
        f32x4 xacc[3] = {};
#pragma unroll
        for (int g = 0; g < 3; g++) {
            xacc[g] = __builtin_amdgcn_mfma_f32_16x16x32_bf16(ax0, Wxreg[g][0], xacc[g], 0, 0, 0);
            xacc[g] = __builtin_amdgcn_mfma_f32_16x16x32_bf16(ax1, Wxreg[g][1], xacc[g], 0, 0, 0);
        }

        const unsigned short* p = hist_t + (size_t)(b0 + l16) * H_ + kbase + q * 8;
        bf16x8 a0, a1, a2, a3, a4, a5, a6, a7;

        // ---- poll: A+B issued together each iteration; break gated on A only ----
        {
            int spins = 0;
            while (true) {
                asm volatile("global_load_dwordx4 %0, %1, off sc0 sc1" : "=v"(a0) : "v"(p));
                asm volatile("global_load_dwordx4 %0, %1, off sc0 sc1" : "=v"(a1) : "v"(p + 32));
                asm volatile("global_load_dwordx4 %0, %1, off sc0 sc1" : "=v"(a2) : "v"(p + 64));
                asm volatile("global_load_dwordx4 %0, %1, off sc0 sc1" : "=v"(a3) : "v"(p + 96));
                asm volatile("global_load_dwordx4 %0, %1, off sc0 sc1" : "=v"(a4) : "v"(p + 128));
                asm volatile("global_load_dwordx4 %0, %1, off sc0 sc1" : "=v"(a5) : "v"(p + 160));
                asm volatile("global_load_dwordx4 %0, %1, off sc0 sc1" : "=v"(a6) : "v"(p + 192));
                asm volatile("global_load_dwordx4 %0, %1, off sc0 sc1" : "=v"(a7) : "v"(p + 224));
                asm volatile("s_waitcnt vmcnt(0)"
                             : "+v"(a0), "+v"(a1), "+v"(a2), "+v"(a3),
                               "+v"(a4), "+v"(a5), "+v"(a6), "+v"(a7) :: "memory");
                int ok = chunk_ok(a0) & chunk_ok(a1) & chunk_ok(a2) & chunk_ok(a3);
                if (__all(ok)) break;
                if (++spins > (1 << 18)) break;   // fail loud, never hang
                __builtin_amdgcn_s_sleep(1);
            }
        }

        f32x4 acc[3] = {};
#pragma unroll
        for (int g = 0; g < 3; g++) {
            acc[g] = __builtin_amdgcn_mfma_f32_16x16x32_bf16(a0, Wreg[g][0], acc[g], 0, 0, 0);
            acc[g] = __builtin_amdgcn_mfma_f32_16x16x32_bf16(a1, Wreg[g][1], acc[g], 0, 0, 0);
            acc[g] = __builtin_amdgcn_mfma_f32_16x16x32_bf16(a2, Wreg[g][2], acc[g], 0, 0, 0);
            acc[g] = __builtin_amdgcn_mfma_f32_16x16x32_bf16(a3, Wreg[g][3], acc[g], 0, 0, 0);
        }

        // ---- check group B (loaded with the passing A iteration); retry on miss ----
        {
            int ok = chunk_ok(a4) & chunk_ok(a5) & chunk_ok(a6) & chunk_ok(a7);
            if (!__all(ok)) {
                int spins = 0;
                while (true) {
                    __builtin_amdgcn_s_sleep(1);
                    asm volatile("global_load_dwordx4 %0, %1, off sc0 sc1" : "=v"(a4) : "v"(p + 128));
                    asm volatile("global_load_dwordx4 %0, %1, off sc0 sc1" : "=v"(a5) : "v"(p + 160));
                    asm volatile("global_load_dwordx4 %0, %1, off sc0 sc1" : "=v"(a6) : "v"(p + 192));
                    asm volatile("global_load_dwordx4 %0, %1, off sc0 sc1" : "=v"(a7) : "v"(p + 224));
                    asm volatile("s_waitcnt vmcnt(0)"
                                 : "+v"(a4), "+v"(a5), "+v"(a6), "+v"(a7) :: "memory");
                    int ok2 = chunk_ok(a4) & chunk_ok(a5) & chunk_ok(a6) & chunk_ok(a7);
                    if (__all(ok2)) break;
                    if (++spins > (1 << 18)) break;
                }
            }
        }
#pragma unroll
        for (int g = 0; g < 3; g++) {
            acc[g] = __builtin_amdgcn_mfma_f32_16x16x32_bf16(a4, Wreg[g][4], acc[g], 0, 0, 0);
            acc[g] = __builtin_amdgcn_mfma_f32_16x16x32_bf16(a5, Wreg[g][5], acc[g], 0, 0, 0);
            acc[g] = __builtin_amdgcn_mfma_f32_16x16x32_bf16(a6, Wreg[g][6], acc[g], 0, 0, 0);
            acc[g] = __builtin_amdgcn_mfma_f32_16x16x32_bf16(a7, Wreg[g][7], acc[g], 0, 0, 0);
        }

        int par = t & 1;
#pragma unroll
        for (int g = 0; g < 3; g++) {
            red[par][wave][g][lane]     = acc[g];
            red[par][wave][3 + g][lane] = xacc[g];
        }
        __syncthreads();

        float gh0 = red[par][0][0][Lp][reg] + red[par][1][0][Lp][reg] + red[par][2][0][Lp][reg] + red[par][3][0][Lp][reg];
        float gh1 = red[par][0][1][Lp][reg] + red[par][1][1][Lp][reg] + red[par][2][1][Lp][reg] + red[par][3][1][Lp][reg];
        float gh2 = red[par][0][2][Lp][reg] + red[par][1][2][Lp][reg] + red[par][2][2][Lp][reg] + red[par][3][2][Lp][reg];
        float xr  = red[par][0][3][Lp][reg] + red[par][1][3][Lp][reg] + red[par][2][3][Lp][reg] + red[par][3][3][Lp][reg];
        float xz  = red[par][0][4][Lp][reg] + red[par][1][4][Lp][reg] + red[par][2][4][Lp][reg] + red[par][3][4][Lp][reg];
        float xn  = red[par][0][5][Lp][reg] + red[par][1][5][Lp][reg] + red[par][2][5][Lp][reg] + red[par][3][5][Lp][reg];

        float r = sigmoid_f(xr + gh0 + bhr);
        float z = sigmoid_f(xz + gh1 + bhz);
        float n = tanh_f(xn + r * (gh2 + bhn));
        float hnew = n + z * (hreg - n);
        hreg = hnew;

        unsigned short hbv = f2bf(hnew);
        if (hbv == 0xAAAAu) hbv = 0xAAABu;   // never store the sentinel

        {
            unsigned short* hp = hist_t1 + (size_t)b * H_ + jg;
            unsigned hv32 = hbv;
            asm volatile("global_store_short %0, %1, off sc0 sc1"
                         :: "v"(hp), "v"(hv32) : "memory");
        }
        yB[((size_t)b * L_ + t) * H_ + jg] = hbv;   // cached; consumed after kernel end
    }
}

// ---- phase 3: logits[m][v] = y[m] @ Wout + bout   (M=16384, K=1024, N=256) ----
__global__ __launch_bounds__(256) void out_gemm(const unsigned short* __restrict__ yB,
                                                const unsigned short* __restrict__ WoutT,
                                                const float* __restrict__ bout,
                                                float* __restrict__ out) {
    int ntile = blockIdx.x;
    int mtile = blockIdx.y;
    int wave = threadIdx.x >> 6, lane = threadIdx.x & 63;
    int l16 = lane & 15, q = lane >> 4;

    int m = mtile * 64 + wave * 16 + l16;
    const bf16x8* Arow = (const bf16x8*)(yB + (size_t)m * H_);
    int n0 = ntile * 64;

    f32x4 acc[4] = {};
    for (int k0 = 0; k0 < H_; k0 += 32) {
        bf16x8 a = Arow[(k0 >> 3) + q];
#pragma unroll
        for (int j = 0; j < 4; j++) {
            const bf16x8* Brow = (const bf16x8*)(WoutT + (size_t)(n0 + j*16 + l16) * H_);
            bf16x8 b = Brow[(k0 >> 3) + q];
            acc[j] = __builtin_amdgcn_mfma_f32_16x16x32_bf16(a, b, acc[j], 0, 0, 0);
        }
    }
    int mrow = mtile * 64 + wave * 16 + q * 4;
#pragma unroll
    for (int j = 0; j < 4; j++) {
        int n = n0 + j * 16 + l16;
        float bias = bout[n];
#pragma unroll
        for (int r = 0; r < 4; r++)
            out[(size_t)(mrow + r) * V_ + n] = acc[j][r] + bias;
    }
}

extern "C" void kernel_launch(void* const* d_in, const int* in_sizes, int n_in,
                              void* d_out, int out_size, void* d_ws, size_t ws_size,
                              hipStream_t stream) {
    const int*   tokens = (const int*)  d_in[0];
    const float* emb    = (const float*)d_in[1];
    const float* Wi     = (const float*)d_in[2];
    const float* Wh     = (const float*)d_in[3];
    const float* bh     = (const float*)d_in[4];
    const float* Wout   = (const float*)d_in[5];
    const float* bout   = (const float*)d_in[6];
    float* out = (float*)d_out;

    char* ws = (char*)d_ws;
    size_t off = 0;
    auto alloc = [&](size_t bytes) -> void* {
        void* p = ws + off;
        off += (bytes + 255) & ~(size_t)255;
        return p;
    };
    unsigned short* WhT   = (unsigned short*)alloc((size_t)H3 * H_ * 2);   // 6 MB
    unsigned short* WiT   = (unsigned short*)alloc((size_t)H3 * E_ * 2);   // 1.5 MB
    unsigned short* WoutT = (unsigned short*)alloc((size_t)V_ * H_ * 2);   // 0.5 MB
    unsigned short* embB  = (unsigned short*)alloc((size_t)V_ * E_ * 2);   // 128 KB
    unsigned short* yB    = (unsigned short*)alloc((size_t)B_ * L_ * H_ * 2); // 32 MB
    unsigned short* hist  = (unsigned short*)alloc((size_t)(L_ + 1) * B_ * H_ * 2); // 33.7 MB

    prep_all<<<12544, 256, 0, stream>>>(Wh, Wi, Wout, emb, WhT, WiT, WoutT,
                                        embB, hist, (uint4*)(hist + (size_t)B_ * H_));

    {
        unsigned short* ah = hist;
        const unsigned short* aW = WhT; const unsigned short* aWx = WiT;
        const unsigned short* ae = embB; const int* at = tokens;
        const float* ab = bh; unsigned short* ay = yB;
        void* args[] = {&ah, &aW, &aWx, &ae, &at, &ab, &ay};
        hipError_t err = hipLaunchCooperativeKernel((void*)gru_persistent,
                                                    dim3(256), dim3(256), args, 0, stream);
        if (err != hipSuccess) {
            // fallback: plain launch; 256 blocks at 1 block/CU co-reside on 256 CUs,
            // and all spins are bounded (fail loud via absmax, not hang)
            gru_persistent<<<dim3(256), dim3(256), 0, stream>>>(
                ah, aW, aWx, ae, at, ab, ay);
        }
    }

    out_gemm<<<dim3(4, 256), 256, 0, stream>>>(yB, WoutT, bout, out);
}

// Round 9
// 872.537 us; speedup vs baseline: 1.0773x; 1.0773x over previous
//
#include <hip/hip_runtime.h>
#include <cstdint>
#include <math.h>

#define B_  64
#define L_  256
#define V_  256
#define E_  256
#define H_  1024
#define H3  3072

typedef __bf16 bf16x8 __attribute__((ext_vector_type(8)));
typedef float  f32x4  __attribute__((ext_vector_type(4)));

__device__ __forceinline__ unsigned short f2bf(float f) {
    union { float f; unsigned u; } v; v.f = f;
    unsigned r = v.u + 0x7fffu + ((v.u >> 16) & 1u);   // round-to-nearest-even
    return (unsigned short)(r >> 16);
}

// ok iff NO 16-bit half of any dword equals the 0xAAAA poison sentinel
__device__ __forceinline__ int chunk_ok(bf16x8 v) {
    union { bf16x8 b; unsigned u[4]; } cv; cv.b = v;
    int ok = 1;
#pragma unroll
    for (int i = 0; i < 4; i++) {
        unsigned x = cv.u[i] ^ 0xAAAAAAAAu;
        ok &= (int)((x & 0xFFFFu) != 0u) & (int)((x >> 16) != 0u);
    }
    return ok;
}

__device__ __forceinline__ float sigmoid_f(float x) {
    return __builtin_amdgcn_rcpf(1.0f + __expf(-x));
}
__device__ __forceinline__ float tanh_f(float x) {
    // tanh(x) = 1 - 2/(e^{2x}+1); saturates correctly at +-inf
    return 1.0f - 2.0f * __builtin_amdgcn_rcpf(1.0f + __expf(2.0f * x));
}

// ---- single prep kernel: 3 transposes + emb convert + h0 zero + hist poison ----
// grid regions: [0,3072) WhT tiles; [3072,3840) WiT; [3840,4096) WoutT;
// [4096,4352) embB+h0; [4352,12544) poison slots 1..256.
__global__ __launch_bounds__(256) void prep_all(
        const float* __restrict__ Wh, const float* __restrict__ Wi,
        const float* __restrict__ Wout, const float* __restrict__ emb,
        unsigned short* __restrict__ WhT, unsigned short* __restrict__ WiT,
        unsigned short* __restrict__ WoutT, unsigned short* __restrict__ embB,
        unsigned short* __restrict__ h0b, uint4* __restrict__ poison) {
    __shared__ unsigned short tile[32][34];
    int bid = blockIdx.x;
    const float* src; unsigned short* dst; int rows, cols, nt, kt;
    if (bid < 3072)      { src = Wh;   dst = WhT;   rows = H_; cols = H3; nt = bid % 96; kt = bid / 96; }
    else if (bid < 3840) { int b = bid - 3072; src = Wi;   dst = WiT;   rows = E_; cols = H3; nt = b % 96; kt = b / 96; }
    else if (bid < 4096) { int b = bid - 3840; src = Wout; dst = WoutT; rows = H_; cols = V_; nt = b % 8;  kt = b / 8; }
    else if (bid < 4352) {
        int idx = (bid - 4096) * 256 + threadIdx.x;   // 65536 = V*E = B*H
        embB[idx] = f2bf(emb[idx]);
        h0b[idx]  = 0;
        return;
    } else {
        size_t T = (size_t)(bid - 4352) * 256 + threadIdx.x;   // 2M uint4 = 33.55 MB
        uint4 v; v.x = v.y = v.z = v.w = 0xAAAAAAAAu;
        poison[T] = v;
        return;
    }
    int n0 = nt * 32, k0 = kt * 32;
    int tx = threadIdx.x & 31, ty = threadIdx.x >> 5;
#pragma unroll
    for (int j = 0; j < 32; j += 8)
        tile[tx][ty + j] = f2bf(src[(size_t)(k0 + ty + j) * cols + (n0 + tx)]);
    __syncthreads();
#pragma unroll
    for (int j = 0; j < 32; j += 8)
        dst[(size_t)(n0 + ty + j) * rows + (k0 + tx)] = tile[ty + j][tx];
}

// ---- phase 2: persistent GRU; round-7 poll structure VERBATIM (A-then-B,
//      sleep per miss, B issued after A passes). Only delta: xw r/z partials
//      seed the Wh accumulators in-register (C-input of the first MFMA), so
//      the LDS reduce shrinks 6 -> 4 slots. xn stays separate (needed for
//      r*hn). Pure post-poll serial-work cut; phase/traffic identical. ----
__global__ __launch_bounds__(256, 1) void gru_persistent(
        unsigned short* __restrict__ hist,        // [257][B][H], slot0=0, rest poisoned
        const unsigned short* __restrict__ WhT,   // [3H][H]
        const unsigned short* __restrict__ WiT,   // [3H][E]
        const unsigned short* __restrict__ embB,  // [V][E]
        const int* __restrict__ tokens,           // [B][L]
        const float* __restrict__ bh,
        unsigned short* __restrict__ yB) {        // [B][L][H]
    __shared__ f32x4 red[2][4][4][64];            // [parity][wave][slot][lane] 32 KB

    int bid = blockIdx.x;
    int btile = bid & 3;
    int jtile = bid >> 2;
    int wave = threadIdx.x >> 6, lane = threadIdx.x & 63;
    int l16 = lane & 15, q = lane >> 4;
    int b0 = btile * 16, j0 = jtile * 16;
    int kbase = wave * 256;

    // ---- pin Wh fragments (96 VGPR/lane) ----
    bf16x8 Wreg[3][8];
#pragma unroll
    for (int g = 0; g < 3; g++) {
        const bf16x8* Brow = (const bf16x8*)(WhT + (size_t)(g * H_ + j0 + l16) * H_);
#pragma unroll
        for (int kk = 0; kk < 8; kk++) {
            Wreg[g][kk] = Brow[(kbase >> 3) + kk * 4 + q];
            asm volatile("" : "+v"(Wreg[g][kk]));
        }
    }
    // ---- pin Wi fragments (24 VGPR/lane) ----
    bf16x8 Wxreg[3][2];
#pragma unroll
    for (int g = 0; g < 3; g++) {
        const bf16x8* Bx = (const bf16x8*)(WiT + (size_t)(g * H_ + j0 + l16) * E_);
#pragma unroll
        for (int c = 0; c < 2; c++) {
            Wxreg[g][c] = Bx[wave * 8 + c * 4 + q];
            asm volatile("" : "+v"(Wxreg[g][c]));
        }
    }

    // ---- per-thread gate mapping / biases / fp32 state ----
    int Lp  = threadIdx.x & 63;
    int reg = threadIdx.x >> 6;
    int b_local = (Lp >> 4) * 4 + reg;
    int j_local = Lp & 15;
    int b = b0 + b_local, jg = j0 + j_local;
    float bhr = bh[jg];
    float bhz = bh[H_ + jg];
    float bhn = bh[2 * H_ + jg];
    asm volatile("" : "+v"(bhr), "+v"(bhz), "+v"(bhn));
    float hreg = 0.0f;

    const int tokrow = (b0 + l16) * L_;

    for (int t = 0; t < L_; t++) {
        const unsigned short* hist_t  = hist + (size_t)t * (B_ * H_);
        unsigned short*       hist_t1 = hist + (size_t)(t + 1) * (B_ * H_);

        // ---- xw partials (h-independent; before the poll) ----
        int tok = tokens[tokrow + t];
        const bf16x8* Ax = (const bf16x8*)(embB + (size_t)tok * E_);
        bf16x8 ax0 = Ax[wave * 8 + q];
        bf16x8 ax1 = Ax[wave * 8 + 4 + q];
        f32x4 xaccR = {}, xaccZ = {}, xaccN = {};
        xaccR = __builtin_amdgcn_mfma_f32_16x16x32_bf16(ax0, Wxreg[0][0], xaccR, 0, 0, 0);
        xaccR = __builtin_amdgcn_mfma_f32_16x16x32_bf16(ax1, Wxreg[0][1], xaccR, 0, 0, 0);
        xaccZ = __builtin_amdgcn_mfma_f32_16x16x32_bf16(ax0, Wxreg[1][0], xaccZ, 0, 0, 0);
        xaccZ = __builtin_amdgcn_mfma_f32_16x16x32_bf16(ax1, Wxreg[1][1], xaccZ, 0, 0, 0);
        xaccN = __builtin_amdgcn_mfma_f32_16x16x32_bf16(ax0, Wxreg[2][0], xaccN, 0, 0, 0);
        xaccN = __builtin_amdgcn_mfma_f32_16x16x32_bf16(ax1, Wxreg[2][1], xaccN, 0, 0, 0);

        const unsigned short* p = hist_t + (size_t)(b0 + l16) * H_ + kbase + q * 8;
        bf16x8 a0, a1, a2, a3, a4, a5, a6, a7;

        // ---- poll group A (chunks 0-3, 128 B); passing iteration = the data ----
        {
            int spins = 0;
            while (true) {
                asm volatile("global_load_dwordx4 %0, %1, off sc0 sc1" : "=v"(a0) : "v"(p));
                asm volatile("global_load_dwordx4 %0, %1, off sc0 sc1" : "=v"(a1) : "v"(p + 32));
                asm volatile("global_load_dwordx4 %0, %1, off sc0 sc1" : "=v"(a2) : "v"(p + 64));
                asm volatile("global_load_dwordx4 %0, %1, off sc0 sc1" : "=v"(a3) : "v"(p + 96));
                asm volatile("s_waitcnt vmcnt(0)"
                             : "+v"(a0), "+v"(a1), "+v"(a2), "+v"(a3) :: "memory");
                int ok = chunk_ok(a0) & chunk_ok(a1) & chunk_ok(a2) & chunk_ok(a3);
                if (__all(ok)) break;
                if (++spins > (1 << 18)) break;   // fail loud, never hang
                __builtin_amdgcn_s_sleep(1);
            }
        }
        // ---- issue group B loads; overlap with group-A MFMAs ----
        asm volatile("global_load_dwordx4 %0, %1, off sc0 sc1" : "=v"(a4) : "v"(p + 128));
        asm volatile("global_load_dwordx4 %0, %1, off sc0 sc1" : "=v"(a5) : "v"(p + 160));
        asm volatile("global_load_dwordx4 %0, %1, off sc0 sc1" : "=v"(a6) : "v"(p + 192));
        asm volatile("global_load_dwordx4 %0, %1, off sc0 sc1" : "=v"(a7) : "v"(p + 224));

        // acc[0]/acc[1] seeded with xw r/z partials (register init, free);
        // acc[2] = hn only — xn must stay separate for r*hn.
        f32x4 acc[3];
        acc[0] = xaccR; acc[1] = xaccZ; acc[2] = (f32x4){};
#pragma unroll
        for (int g = 0; g < 3; g++) {
            acc[g] = __builtin_amdgcn_mfma_f32_16x16x32_bf16(a0, Wreg[g][0], acc[g], 0, 0, 0);
            acc[g] = __builtin_amdgcn_mfma_f32_16x16x32_bf16(a1, Wreg[g][1], acc[g], 0, 0, 0);
            acc[g] = __builtin_amdgcn_mfma_f32_16x16x32_bf16(a2, Wreg[g][2], acc[g], 0, 0, 0);
            acc[g] = __builtin_amdgcn_mfma_f32_16x16x32_bf16(a3, Wreg[g][3], acc[g], 0, 0, 0);
        }

        // ---- wait + check group B; retry only B on miss ----
        asm volatile("s_waitcnt vmcnt(0)"
                     : "+v"(a4), "+v"(a5), "+v"(a6), "+v"(a7) :: "memory");
        {
            int ok = chunk_ok(a4) & chunk_ok(a5) & chunk_ok(a6) & chunk_ok(a7);
            if (!__all(ok)) {
                int spins = 0;
                while (true) {
                    __builtin_amdgcn_s_sleep(1);
                    asm volatile("global_load_dwordx4 %0, %1, off sc0 sc1" : "=v"(a4) : "v"(p + 128));
                    asm volatile("global_load_dwordx4 %0, %1, off sc0 sc1" : "=v"(a5) : "v"(p + 160));
                    asm volatile("global_load_dwordx4 %0, %1, off sc0 sc1" : "=v"(a6) : "v"(p + 192));
                    asm volatile("global_load_dwordx4 %0, %1, off sc0 sc1" : "=v"(a7) : "v"(p + 224));
                    asm volatile("s_waitcnt vmcnt(0)"
                                 : "+v"(a4), "+v"(a5), "+v"(a6), "+v"(a7) :: "memory");
                    int ok2 = chunk_ok(a4) & chunk_ok(a5) & chunk_ok(a6) & chunk_ok(a7);
                    if (__all(ok2)) break;
                    if (++spins > (1 << 18)) break;
                }
            }
        }
#pragma unroll
        for (int g = 0; g < 3; g++) {
            acc[g] = __builtin_amdgcn_mfma_f32_16x16x32_bf16(a4, Wreg[g][4], acc[g], 0, 0, 0);
            acc[g] = __builtin_amdgcn_mfma_f32_16x16x32_bf16(a5, Wreg[g][5], acc[g], 0, 0, 0);
            acc[g] = __builtin_amdgcn_mfma_f32_16x16x32_bf16(a6, Wreg[g][6], acc[g], 0, 0, 0);
            acc[g] = __builtin_amdgcn_mfma_f32_16x16x32_bf16(a7, Wreg[g][7], acc[g], 0, 0, 0);
        }

        int par = t & 1;
#pragma unroll
        for (int g = 0; g < 3; g++)
            red[par][wave][g][lane] = acc[g];
        red[par][wave][3][lane] = xaccN;
        __syncthreads();

        float s0 = red[par][0][0][Lp][reg] + red[par][1][0][Lp][reg] + red[par][2][0][Lp][reg] + red[par][3][0][Lp][reg];
        float s1 = red[par][0][1][Lp][reg] + red[par][1][1][Lp][reg] + red[par][2][1][Lp][reg] + red[par][3][1][Lp][reg];
        float s2 = red[par][0][2][Lp][reg] + red[par][1][2][Lp][reg] + red[par][2][2][Lp][reg] + red[par][3][2][Lp][reg];
        float s3 = red[par][0][3][Lp][reg] + red[par][1][3][Lp][reg] + red[par][2][3][Lp][reg] + red[par][3][3][Lp][reg];

        float r = sigmoid_f(s0 + bhr);            // xr + hr (folded)
        float z = sigmoid_f(s1 + bhz);            // xz + hz (folded)
        float n = tanh_f(s3 + r * (s2 + bhn));    // xn + r*(hn + bhn)
        float hnew = n + z * (hreg - n);
        hreg = hnew;

        unsigned short hbv = f2bf(hnew);
        if (hbv == 0xAAAAu) hbv = 0xAAABu;   // never store the sentinel

        {
            unsigned short* hp = hist_t1 + (size_t)b * H_ + jg;
            unsigned hv32 = hbv;
            asm volatile("global_store_short %0, %1, off sc0 sc1"
                         :: "v"(hp), "v"(hv32) : "memory");
        }
        yB[((size_t)b * L_ + t) * H_ + jg] = hbv;   // cached; consumed after kernel end
    }
}

// ---- phase 3: logits[m][v] = y[m] @ Wout + bout   (M=16384, K=1024, N=256) ----
__global__ __launch_bounds__(256) void out_gemm(const unsigned short* __restrict__ yB,
                                                const unsigned short* __restrict__ WoutT,
                                                const float* __restrict__ bout,
                                                float* __restrict__ out) {
    int ntile = blockIdx.x;
    int mtile = blockIdx.y;
    int wave = threadIdx.x >> 6, lane = threadIdx.x & 63;
    int l16 = lane & 15, q = lane >> 4;

    int m = mtile * 64 + wave * 16 + l16;
    const bf16x8* Arow = (const bf16x8*)(yB + (size_t)m * H_);
    int n0 = ntile * 64;

    f32x4 acc[4] = {};
    for (int k0 = 0; k0 < H_; k0 += 32) {
        bf16x8 a = Arow[(k0 >> 3) + q];
#pragma unroll
        for (int j = 0; j < 4; j++) {
            const bf16x8* Brow = (const bf16x8*)(WoutT + (size_t)(n0 + j*16 + l16) * H_);
            bf16x8 b = Brow[(k0 >> 3) + q];
            acc[j] = __builtin_amdgcn_mfma_f32_16x16x32_bf16(a, b, acc[j], 0, 0, 0);
        }
    }
    int mrow = mtile * 64 + wave * 16 + q * 4;
#pragma unroll
    for (int j = 0; j < 4; j++) {
        int n = n0 + j * 16 + l16;
        float bias = bout[n];
#pragma unroll
        for (int r = 0; r < 4; r++)
            out[(size_t)(mrow + r) * V_ + n] = acc[j][r] + bias;
    }
}

extern "C" void kernel_launch(void* const* d_in, const int* in_sizes, int n_in,
                              void* d_out, int out_size, void* d_ws, size_t ws_size,
                              hipStream_t stream) {
    const int*   tokens = (const int*)  d_in[0];
    const float* emb    = (const float*)d_in[1];
    const float* Wi     = (const float*)d_in[2];
    const float* Wh     = (const float*)d_in[3];
    const float* bh     = (const float*)d_in[4];
    const float* Wout   = (const float*)d_in[5];
    const float* bout   = (const float*)d_in[6];
    float* out = (float*)d_out;

    char* ws = (char*)d_ws;
    size_t off = 0;
    auto alloc = [&](size_t bytes) -> void* {
        void* p = ws + off;
        off += (bytes + 255) & ~(size_t)255;
        return p;
    };
    unsigned short* WhT   = (unsigned short*)alloc((size_t)H3 * H_ * 2);   // 6 MB
    unsigned short* WiT   = (unsigned short*)alloc((size_t)H3 * E_ * 2);   // 1.5 MB
    unsigned short* WoutT = (unsigned short*)alloc((size_t)V_ * H_ * 2);   // 0.5 MB
    unsigned short* embB  = (unsigned short*)alloc((size_t)V_ * E_ * 2);   // 128 KB
    unsigned short* yB    = (unsigned short*)alloc((size_t)B_ * L_ * H_ * 2); // 32 MB
    unsigned short* hist  = (unsigned short*)alloc((size_t)(L_ + 1) * B_ * H_ * 2); // 33.7 MB

    prep_all<<<12544, 256, 0, stream>>>(Wh, Wi, Wout, emb, WhT, WiT, WoutT,
                                        embB, hist, (uint4*)(hist + (size_t)B_ * H_));

    {
        unsigned short* ah = hist;
        const unsigned short* aW = WhT; const unsigned short* aWx = WiT;
        const unsigned short* ae = embB; const int* at = tokens;
        const float* ab = bh; unsigned short* ay = yB;
        void* args[] = {&ah, &aW, &aWx, &ae, &at, &ab, &ay};
        hipError_t err = hipLaunchCooperativeKernel((void*)gru_persistent,
                                                    dim3(256), dim3(256), args, 0, stream);
        if (err != hipSuccess) {
            // fallback: plain launch; 256 blocks at 1 block/CU co-reside on 256 CUs,
            // and all spins are bounded (fail loud via absmax, not hang)
            gru_persistent<<<dim3(256), dim3(256), 0, stream>>>(
                ah, aW, aWx, ae, at, ab, ay);
        }
    }

    out_gemm<<<dim3(4, 256), 256, 0, stream>>>(yB, WoutT, bout, out);
}

// Round 10
// 863.783 us; speedup vs baseline: 1.0883x; 1.0101x over previous
//
#include <hip/hip_runtime.h>
#include <cstdint>
#include <math.h>

#define B_  64
#define L_  256
#define V_  256
#define E_  256
#define H_  1024
#define H3  3072

typedef __bf16 bf16x8 __attribute__((ext_vector_type(8)));
typedef float  f32x4  __attribute__((ext_vector_type(4)));

__device__ __forceinline__ unsigned short f2bf(float f) {
    union { float f; unsigned u; } v; v.f = f;
    unsigned r = v.u + 0x7fffu + ((v.u >> 16) & 1u);   // round-to-nearest-even
    return (unsigned short)(r >> 16);
}

// ok iff NO 16-bit half of any dword equals the 0xAAAA poison sentinel
__device__ __forceinline__ int chunk_ok(bf16x8 v) {
    union { bf16x8 b; unsigned u[4]; } cv; cv.b = v;
    int ok = 1;
#pragma unroll
    for (int i = 0; i < 4; i++) {
        unsigned x = cv.u[i] ^ 0xAAAAAAAAu;
        ok &= (int)((x & 0xFFFFu) != 0u) & (int)((x >> 16) != 0u);
    }
    return ok;
}

__device__ __forceinline__ float sigmoid_f(float x) {
    return __builtin_amdgcn_rcpf(1.0f + __expf(-x));
}
__device__ __forceinline__ float tanh_f(float x) {
    // tanh(x) = 1 - 2/(e^{2x}+1); saturates correctly at +-inf
    return 1.0f - 2.0f * __builtin_amdgcn_rcpf(1.0f + __expf(2.0f * x));
}

// ---- single prep kernel: 3 transposes + emb convert + h0 zero + hist poison ----
// grid regions: [0,3072) WhT tiles; [3072,3840) WiT; [3840,4096) WoutT;
// [4096,4352) embB+h0; [4352,12544) poison slots 1..256.
__global__ __launch_bounds__(256) void prep_all(
        const float* __restrict__ Wh, const float* __restrict__ Wi,
        const float* __restrict__ Wout, const float* __restrict__ emb,
        unsigned short* __restrict__ WhT, unsigned short* __restrict__ WiT,
        unsigned short* __restrict__ WoutT, unsigned short* __restrict__ embB,
        unsigned short* __restrict__ h0b, uint4* __restrict__ poison) {
    __shared__ unsigned short tile[32][34];
    int bid = blockIdx.x;
    const float* src; unsigned short* dst; int rows, cols, nt, kt;
    if (bid < 3072)      { src = Wh;   dst = WhT;   rows = H_; cols = H3; nt = bid % 96; kt = bid / 96; }
    else if (bid < 3840) { int b = bid - 3072; src = Wi;   dst = WiT;   rows = E_; cols = H3; nt = b % 96; kt = b / 96; }
    else if (bid < 4096) { int b = bid - 3840; src = Wout; dst = WoutT; rows = H_; cols = V_; nt = b % 8;  kt = b / 8; }
    else if (bid < 4352) {
        int idx = (bid - 4096) * 256 + threadIdx.x;   // 65536 = V*E = B*H
        embB[idx] = f2bf(emb[idx]);
        h0b[idx]  = 0;
        return;
    } else {
        size_t T = (size_t)(bid - 4352) * 256 + threadIdx.x;   // 2M uint4 = 33.55 MB
        uint4 v; v.x = v.y = v.z = v.w = 0xAAAAAAAAu;
        poison[T] = v;
        return;
    }
    int n0 = nt * 32, k0 = kt * 32;
    int tx = threadIdx.x & 31, ty = threadIdx.x >> 5;
#pragma unroll
    for (int j = 0; j < 32; j += 8)
        tile[tx][ty + j] = f2bf(src[(size_t)(k0 + ty + j) * cols + (n0 + tx)]);
    __syncthreads();
#pragma unroll
    for (int j = 0; j < 32; j += 8)
        dst[(size_t)(n0 + ty + j) * rows + (k0 + tx)] = tile[ty + j][tx];
}

// ---- phase 2: persistent GRU; round-9 structure VERBATIM minus the yB
//      store: hist IS the output (hist[t+1][b][j] == y[b][t][j]); out_gemm
//      reads hist directly. Epilogue loses one cached store; write traffic
//      behind the coherent polls halves. Poll phase/semantics untouched. ----
__global__ __launch_bounds__(256, 1) void gru_persistent(
        unsigned short* __restrict__ hist,        // [257][B][H], slot0=0, rest poisoned
        const unsigned short* __restrict__ WhT,   // [3H][H]
        const unsigned short* __restrict__ WiT,   // [3H][E]
        const unsigned short* __restrict__ embB,  // [V][E]
        const int* __restrict__ tokens,           // [B][L]
        const float* __restrict__ bh) {
    __shared__ f32x4 red[2][4][4][64];            // [parity][wave][slot][lane] 32 KB

    int bid = blockIdx.x;
    int btile = bid & 3;
    int jtile = bid >> 2;
    int wave = threadIdx.x >> 6, lane = threadIdx.x & 63;
    int l16 = lane & 15, q = lane >> 4;
    int b0 = btile * 16, j0 = jtile * 16;
    int kbase = wave * 256;

    // ---- pin Wh fragments (96 VGPR/lane) ----
    bf16x8 Wreg[3][8];
#pragma unroll
    for (int g = 0; g < 3; g++) {
        const bf16x8* Brow = (const bf16x8*)(WhT + (size_t)(g * H_ + j0 + l16) * H_);
#pragma unroll
        for (int kk = 0; kk < 8; kk++) {
            Wreg[g][kk] = Brow[(kbase >> 3) + kk * 4 + q];
            asm volatile("" : "+v"(Wreg[g][kk]));
        }
    }
    // ---- pin Wi fragments (24 VGPR/lane) ----
    bf16x8 Wxreg[3][2];
#pragma unroll
    for (int g = 0; g < 3; g++) {
        const bf16x8* Bx = (const bf16x8*)(WiT + (size_t)(g * H_ + j0 + l16) * E_);
#pragma unroll
        for (int c = 0; c < 2; c++) {
            Wxreg[g][c] = Bx[wave * 8 + c * 4 + q];
            asm volatile("" : "+v"(Wxreg[g][c]));
        }
    }

    // ---- per-thread gate mapping / biases / fp32 state ----
    int Lp  = threadIdx.x & 63;
    int reg = threadIdx.x >> 6;
    int b_local = (Lp >> 4) * 4 + reg;
    int j_local = Lp & 15;
    int b = b0 + b_local, jg = j0 + j_local;
    float bhr = bh[jg];
    float bhz = bh[H_ + jg];
    float bhn = bh[2 * H_ + jg];
    asm volatile("" : "+v"(bhr), "+v"(bhz), "+v"(bhn));
    float hreg = 0.0f;

    const int tokrow = (b0 + l16) * L_;

    for (int t = 0; t < L_; t++) {
        const unsigned short* hist_t  = hist + (size_t)t * (B_ * H_);
        unsigned short*       hist_t1 = hist + (size_t)(t + 1) * (B_ * H_);

        // ---- xw partials (h-independent; before the poll) ----
        int tok = tokens[tokrow + t];
        const bf16x8* Ax = (const bf16x8*)(embB + (size_t)tok * E_);
        bf16x8 ax0 = Ax[wave * 8 + q];
        bf16x8 ax1 = Ax[wave * 8 + 4 + q];
        f32x4 xaccR = {}, xaccZ = {}, xaccN = {};
        xaccR = __builtin_amdgcn_mfma_f32_16x16x32_bf16(ax0, Wxreg[0][0], xaccR, 0, 0, 0);
        xaccR = __builtin_amdgcn_mfma_f32_16x16x32_bf16(ax1, Wxreg[0][1], xaccR, 0, 0, 0);
        xaccZ = __builtin_amdgcn_mfma_f32_16x16x32_bf16(ax0, Wxreg[1][0], xaccZ, 0, 0, 0);
        xaccZ = __builtin_amdgcn_mfma_f32_16x16x32_bf16(ax1, Wxreg[1][1], xaccZ, 0, 0, 0);
        xaccN = __builtin_amdgcn_mfma_f32_16x16x32_bf16(ax0, Wxreg[2][0], xaccN, 0, 0, 0);
        xaccN = __builtin_amdgcn_mfma_f32_16x16x32_bf16(ax1, Wxreg[2][1], xaccN, 0, 0, 0);

        const unsigned short* p = hist_t + (size_t)(b0 + l16) * H_ + kbase + q * 8;
        bf16x8 a0, a1, a2, a3, a4, a5, a6, a7;

        // ---- poll group A (chunks 0-3, 128 B); passing iteration = the data ----
        {
            int spins = 0;
            while (true) {
                asm volatile("global_load_dwordx4 %0, %1, off sc0 sc1" : "=v"(a0) : "v"(p));
                asm volatile("global_load_dwordx4 %0, %1, off sc0 sc1" : "=v"(a1) : "v"(p + 32));
                asm volatile("global_load_dwordx4 %0, %1, off sc0 sc1" : "=v"(a2) : "v"(p + 64));
                asm volatile("global_load_dwordx4 %0, %1, off sc0 sc1" : "=v"(a3) : "v"(p + 96));
                asm volatile("s_waitcnt vmcnt(0)"
                             : "+v"(a0), "+v"(a1), "+v"(a2), "+v"(a3) :: "memory");
                int ok = chunk_ok(a0) & chunk_ok(a1) & chunk_ok(a2) & chunk_ok(a3);
                if (__all(ok)) break;
                if (++spins > (1 << 18)) break;   // fail loud, never hang
                __builtin_amdgcn_s_sleep(1);
            }
        }
        // ---- issue group B loads; overlap with group-A MFMAs ----
        asm volatile("global_load_dwordx4 %0, %1, off sc0 sc1" : "=v"(a4) : "v"(p + 128));
        asm volatile("global_load_dwordx4 %0, %1, off sc0 sc1" : "=v"(a5) : "v"(p + 160));
        asm volatile("global_load_dwordx4 %0, %1, off sc0 sc1" : "=v"(a6) : "v"(p + 192));
        asm volatile("global_load_dwordx4 %0, %1, off sc0 sc1" : "=v"(a7) : "v"(p + 224));

        // acc[0]/acc[1] seeded with xw r/z partials (register init, free);
        // acc[2] = hn only — xn must stay separate for r*hn.
        f32x4 acc[3];
        acc[0] = xaccR; acc[1] = xaccZ; acc[2] = (f32x4){};
#pragma unroll
        for (int g = 0; g < 3; g++) {
            acc[g] = __builtin_amdgcn_mfma_f32_16x16x32_bf16(a0, Wreg[g][0], acc[g], 0, 0, 0);
            acc[g] = __builtin_amdgcn_mfma_f32_16x16x32_bf16(a1, Wreg[g][1], acc[g], 0, 0, 0);
            acc[g] = __builtin_amdgcn_mfma_f32_16x16x32_bf16(a2, Wreg[g][2], acc[g], 0, 0, 0);
            acc[g] = __builtin_amdgcn_mfma_f32_16x16x32_bf16(a3, Wreg[g][3], acc[g], 0, 0, 0);
        }

        // ---- wait + check group B; retry only B on miss ----
        asm volatile("s_waitcnt vmcnt(0)"
                     : "+v"(a4), "+v"(a5), "+v"(a6), "+v"(a7) :: "memory");
        {
            int ok = chunk_ok(a4) & chunk_ok(a5) & chunk_ok(a6) & chunk_ok(a7);
            if (!__all(ok)) {
                int spins = 0;
                while (true) {
                    __builtin_amdgcn_s_sleep(1);
                    asm volatile("global_load_dwordx4 %0, %1, off sc0 sc1" : "=v"(a4) : "v"(p + 128));
                    asm volatile("global_load_dwordx4 %0, %1, off sc0 sc1" : "=v"(a5) : "v"(p + 160));
                    asm volatile("global_load_dwordx4 %0, %1, off sc0 sc1" : "=v"(a6) : "v"(p + 192));
                    asm volatile("global_load_dwordx4 %0, %1, off sc0 sc1" : "=v"(a7) : "v"(p + 224));
                    asm volatile("s_waitcnt vmcnt(0)"
                                 : "+v"(a4), "+v"(a5), "+v"(a6), "+v"(a7) :: "memory");
                    int ok2 = chunk_ok(a4) & chunk_ok(a5) & chunk_ok(a6) & chunk_ok(a7);
                    if (__all(ok2)) break;
                    if (++spins > (1 << 18)) break;
                }
            }
        }
#pragma unroll
        for (int g = 0; g < 3; g++) {
            acc[g] = __builtin_amdgcn_mfma_f32_16x16x32_bf16(a4, Wreg[g][4], acc[g], 0, 0, 0);
            acc[g] = __builtin_amdgcn_mfma_f32_16x16x32_bf16(a5, Wreg[g][5], acc[g], 0, 0, 0);
            acc[g] = __builtin_amdgcn_mfma_f32_16x16x32_bf16(a6, Wreg[g][6], acc[g], 0, 0, 0);
            acc[g] = __builtin_amdgcn_mfma_f32_16x16x32_bf16(a7, Wreg[g][7], acc[g], 0, 0, 0);
        }

        int par = t & 1;
#pragma unroll
        for (int g = 0; g < 3; g++)
            red[par][wave][g][lane] = acc[g];
        red[par][wave][3][lane] = xaccN;
        __syncthreads();

        float s0 = red[par][0][0][Lp][reg] + red[par][1][0][Lp][reg] + red[par][2][0][Lp][reg] + red[par][3][0][Lp][reg];
        float s1 = red[par][0][1][Lp][reg] + red[par][1][1][Lp][reg] + red[par][2][1][Lp][reg] + red[par][3][1][Lp][reg];
        float s2 = red[par][0][2][Lp][reg] + red[par][1][2][Lp][reg] + red[par][2][2][Lp][reg] + red[par][3][2][Lp][reg];
        float s3 = red[par][0][3][Lp][reg] + red[par][1][3][Lp][reg] + red[par][2][3][Lp][reg] + red[par][3][3][Lp][reg];

        float r = sigmoid_f(s0 + bhr);            // xr + hr (folded)
        float z = sigmoid_f(s1 + bhz);            // xz + hz (folded)
        float n = tanh_f(s3 + r * (s2 + bhn));    // xn + r*(hn + bhn)
        float hnew = n + z * (hreg - n);
        hreg = hnew;

        unsigned short hbv = f2bf(hnew);
        if (hbv == 0xAAAAu) hbv = 0xAAABu;   // never store the sentinel

        {
            unsigned short* hp = hist_t1 + (size_t)b * H_ + jg;
            unsigned hv32 = hbv;
            asm volatile("global_store_short %0, %1, off sc0 sc1"
                         :: "v"(hp), "v"(hv32) : "memory");
        }
        // no yB store: hist[t+1] IS y[.][t]; out_gemm reads hist directly
    }
}

// ---- phase 3: logits[m][v] = y[m] @ Wout + bout   (M=16384, K=1024, N=256)
//      A-row for m=(b,t) comes straight from hist[t+1][b][·]. ----
__global__ __launch_bounds__(256) void out_gemm(const unsigned short* __restrict__ hist,
                                                const unsigned short* __restrict__ WoutT,
                                                const float* __restrict__ bout,
                                                float* __restrict__ out) {
    int ntile = blockIdx.x;
    int mtile = blockIdx.y;
    int wave = threadIdx.x >> 6, lane = threadIdx.x & 63;
    int l16 = lane & 15, q = lane >> 4;

    int m = mtile * 64 + wave * 16 + l16;
    int bb = m >> 8, tt = m & 255;                // m = b*L + t
    const bf16x8* Arow = (const bf16x8*)(hist + (size_t)(tt + 1) * (B_ * H_) + (size_t)bb * H_);
    int n0 = ntile * 64;

    f32x4 acc[4] = {};
    for (int k0 = 0; k0 < H_; k0 += 32) {
        bf16x8 a = Arow[(k0 >> 3) + q];
#pragma unroll
        for (int j = 0; j < 4; j++) {
            const bf16x8* Brow = (const bf16x8*)(WoutT + (size_t)(n0 + j*16 + l16) * H_);
            bf16x8 b = Brow[(k0 >> 3) + q];
            acc[j] = __builtin_amdgcn_mfma_f32_16x16x32_bf16(a, b, acc[j], 0, 0, 0);
        }
    }
    int mrow = mtile * 64 + wave * 16 + q * 4;
#pragma unroll
    for (int j = 0; j < 4; j++) {
        int n = n0 + j * 16 + l16;
        float bias = bout[n];
#pragma unroll
        for (int r = 0; r < 4; r++)
            out[(size_t)(mrow + r) * V_ + n] = acc[j][r] + bias;
    }
}

extern "C" void kernel_launch(void* const* d_in, const int* in_sizes, int n_in,
                              void* d_out, int out_size, void* d_ws, size_t ws_size,
                              hipStream_t stream) {
    const int*   tokens = (const int*)  d_in[0];
    const float* emb    = (const float*)d_in[1];
    const float* Wi     = (const float*)d_in[2];
    const float* Wh     = (const float*)d_in[3];
    const float* bh     = (const float*)d_in[4];
    const float* Wout   = (const float*)d_in[5];
    const float* bout   = (const float*)d_in[6];
    float* out = (float*)d_out;

    char* ws = (char*)d_ws;
    size_t off = 0;
    auto alloc = [&](size_t bytes) -> void* {
        void* p = ws + off;
        off += (bytes + 255) & ~(size_t)255;
        return p;
    };
    unsigned short* WhT   = (unsigned short*)alloc((size_t)H3 * H_ * 2);   // 6 MB
    unsigned short* WiT   = (unsigned short*)alloc((size_t)H3 * E_ * 2);   // 1.5 MB
    unsigned short* WoutT = (unsigned short*)alloc((size_t)V_ * H_ * 2);   // 0.5 MB
    unsigned short* embB  = (unsigned short*)alloc((size_t)V_ * E_ * 2);   // 128 KB
    unsigned short* hist  = (unsigned short*)alloc((size_t)(L_ + 1) * B_ * H_ * 2); // 33.7 MB

    prep_all<<<12544, 256, 0, stream>>>(Wh, Wi, Wout, emb, WhT, WiT, WoutT,
                                        embB, hist, (uint4*)(hist + (size_t)B_ * H_));

    {
        unsigned short* ah = hist;
        const unsigned short* aW = WhT; const unsigned short* aWx = WiT;
        const unsigned short* ae = embB; const int* at = tokens;
        const float* ab = bh;
        void* args[] = {&ah, &aW, &aWx, &ae, &at, &ab};
        hipError_t err = hipLaunchCooperativeKernel((void*)gru_persistent,
                                                    dim3(256), dim3(256), args, 0, stream);
        if (err != hipSuccess) {
            // fallback: plain launch; 256 blocks at 1 block/CU co-reside on 256 CUs,
            // and all spins are bounded (fail loud via absmax, not hang)
            gru_persistent<<<dim3(256), dim3(256), 0, stream>>>(
                ah, aW, aWx, ae, at, ab);
        }
    }

    out_gemm<<<dim3(4, 256), 256, 0, stream>>>(hist, WoutT, bout, out);
}